// Round 5
// baseline (311.122 us; speedup 1.0000x reference)
//
#include <hip/hip_runtime.h>
#include <cstdint>
#include <cstddef>

#define B_   4
#define T_   2048
#define D_   1024
#define H_   8
#define DK_  64
#define HD_  512      // H*DK
#define CH_  64       // chunk length
#define NC_  32       // T_/CH_
#define EPS_ 1e-6f

typedef __attribute__((ext_vector_type(4))) float f32x4;
typedef __attribute__((ext_vector_type(8))) short s16x8;

__device__ __forceinline__ unsigned short f2bf(float f) {
    unsigned int x = __float_as_uint(f);
    unsigned int r = (x + 0x7FFFu + ((x >> 16) & 1u)) >> 16;
    return (unsigned short)r;
}
__device__ __forceinline__ float bf2f(unsigned short u) {
    return __uint_as_float(((unsigned int)u) << 16);
}
// async global->LDS, 16B per lane; LDS dest = wave-uniform base + lane*16
__device__ __forceinline__ void gl_lds16(const unsigned short* g, unsigned short* l) {
    __builtin_amdgcn_global_load_lds(
        (const __attribute__((address_space(1))) unsigned int*)g,
        (__attribute__((address_space(3))) unsigned int*)l, 16, 0, 0);
}

// ---------------- K0: fused fp32 -> bf16 convert for all six tensors ----------------
__global__ __launch_bounds__(256) void k_cvt_all(
    const float* __restrict__ x,
    const float* __restrict__ wq, const float* __restrict__ wk,
    const float* __restrict__ wv, const float* __restrict__ wgw,
    const float* __restrict__ wo,
    unsigned short* __restrict__ xb,
    unsigned short* __restrict__ wqb, unsigned short* __restrict__ wkb,
    unsigned short* __restrict__ wvb, unsigned short* __restrict__ wgb,
    unsigned short* __restrict__ wob)
{
    int bid = blockIdx.x;
    const float* src; unsigned short* dst; int idx;
    if (bid < 8192) {
        src = x; dst = xb; idx = bid * 256 + threadIdx.x;
    } else {
        int r = bid - 8192;
        int w = r >> 9;
        idx = (r & 511) * 256 + threadIdx.x;
        switch (w) {
            case 0:  src = wq;  dst = wqb; break;
            case 1:  src = wk;  dst = wkb; break;
            case 2:  src = wv;  dst = wvb; break;
            case 3:  src = wgw; dst = wgb; break;
            default: src = wo;  dst = wob; break;
        }
    }
    float4 v = ((const float4*)src)[idx];
    ushort4 o;
    o.x = f2bf(v.x); o.y = f2bf(v.y); o.z = f2bf(v.z); o.w = f2bf(v.w);
    ((ushort4*)dst)[idx] = o;
}

// ---------------- K1: fused QKVG GEMM, 256x256 tile, 4-phase schedule (round-3 best: 57.7us) ----------------
__global__ __launch_bounds__(512, 2) void k_gemm_qkvg(
    const unsigned short* __restrict__ xb,
    const unsigned short* __restrict__ wqb, const unsigned short* __restrict__ wkb,
    const unsigned short* __restrict__ wvb, const unsigned short* __restrict__ wgb,
    const float* __restrict__ bias,
    unsigned short* __restrict__ qo, unsigned short* __restrict__ ko,
    unsigned short* __restrict__ vo, unsigned short* __restrict__ go)
{
    __shared__ unsigned short As[2][256 * 64];   // 64KB
    __shared__ unsigned short Bs[2][256 * 64];   // 64KB
    const int tid = threadIdx.x;
    const int id  = blockIdx.x;                  // 0..255
    const int xcd = id & 7, per = id >> 3;       // per 0..31
    const int mtile = xcd * 4 + (per & 3);       // 0..31
    const int ntile = per >> 2;                  // 0..7
    const int which = ntile >> 1;                // 0=Q 1=K 2=V 3=G
    const int nb    = ntile & 1;
    const int m0    = mtile * 256;
    const int n0    = nb * 256;
    const unsigned short* Wp = (which == 0) ? wqb : (which == 1) ? wkb : (which == 2) ? wvb : wgb;
    unsigned short* Op       = (which == 0) ? qo  : (which == 1) ? ko  : (which == 2) ? vo  : go;
    const int K = D_;
    const int NIT = K / 64;                      // 16

    const int lane = tid & 63, wave = tid >> 6;
    const int wm = (wave >> 2) * 128, wn = (wave & 3) * 64;
    const int r16 = lane & 15, quad = lane >> 4;
    const int lrow = lane >> 3, lseg = lane & 7;
    const int sseg = lseg ^ lrow;                // XOR swizzle key (write side via global addr)
    const int rx   = r16 & 7;                    // read-side swizzle key

    f32x4 acc[8][4];
    #pragma unroll
    for (int a = 0; a < 8; a++)
        #pragma unroll
        for (int b = 0; b < 4; b++) acc[a][b] = 0.0f;

    auto stageA = [&](int buf, int ko_) {
        #pragma unroll
        for (int i = 0; i < 4; i++) {
            int chunk = wave * 4 + i;
            int row = chunk * 8 + lrow;
            gl_lds16(xb + (size_t)(m0 + row) * K + ko_ + sseg * 8, &As[buf][chunk * 512]);
        }
    };
    auto stageB = [&](int buf, int ko_) {
        #pragma unroll
        for (int i = 0; i < 4; i++) {
            int chunk = wave * 4 + i;
            int row = chunk * 8 + lrow;
            gl_lds16(Wp + (size_t)(n0 + row) * K + ko_ + sseg * 8, &Bs[buf][chunk * 512]);
        }
    };
    auto rdA = [&](int buf, int row, int gb) -> s16x8 {
        return *(const s16x8*)&As[buf][row * 64 + (((gb + quad) ^ rx) << 3)];
    };
    auto rdB = [&](int buf, int row, int gb) -> s16x8 {
        return *(const s16x8*)&Bs[buf][row * 64 + (((gb + quad) ^ rx) << 3)];
    };

    stageA(0, 0); stageB(0, 0);
    for (int it = 0; it < NIT; ++it) {
        const int buf = it & 1;
        asm volatile("s_waitcnt vmcnt(0)" ::: "memory");
        __builtin_amdgcn_s_barrier();

        s16x8 af[4], bfr[4];
        // Phase 0: m-half0 x kk0
        #pragma unroll
        for (int mt = 0; mt < 4; mt++) af[mt]  = rdA(buf, wm + mt * 16 + r16, 0);
        #pragma unroll
        for (int nt = 0; nt < 4; nt++) bfr[nt] = rdB(buf, wn + nt * 16 + r16, 0);
        if (it + 1 < NIT) stageA(buf ^ 1, (it + 1) * 64);
        __builtin_amdgcn_s_barrier();
        asm volatile("s_waitcnt lgkmcnt(0)" ::: "memory");
        __builtin_amdgcn_sched_barrier(0);
        __builtin_amdgcn_s_setprio(1);
        #pragma unroll
        for (int mt = 0; mt < 4; mt++)
            #pragma unroll
            for (int nt = 0; nt < 4; nt++)
                acc[mt][nt] = __builtin_amdgcn_mfma_f32_16x16x32_bf16(af[mt], bfr[nt], acc[mt][nt], 0, 0, 0);
        __builtin_amdgcn_s_setprio(0);
        __builtin_amdgcn_s_barrier();

        // Phase 1: m-half1 x kk0 (bfr reused)
        #pragma unroll
        for (int mt = 0; mt < 4; mt++) af[mt] = rdA(buf, wm + (mt + 4) * 16 + r16, 0);
        if (it + 1 < NIT) stageB(buf ^ 1, (it + 1) * 64);
        __builtin_amdgcn_s_barrier();
        asm volatile("s_waitcnt lgkmcnt(0)" ::: "memory");
        __builtin_amdgcn_sched_barrier(0);
        __builtin_amdgcn_s_setprio(1);
        #pragma unroll
        for (int mt = 0; mt < 4; mt++)
            #pragma unroll
            for (int nt = 0; nt < 4; nt++)
                acc[mt + 4][nt] = __builtin_amdgcn_mfma_f32_16x16x32_bf16(af[mt], bfr[nt], acc[mt + 4][nt], 0, 0, 0);
        __builtin_amdgcn_s_setprio(0);
        __builtin_amdgcn_s_barrier();

        // Phase 2: m-half0 x kk1
        #pragma unroll
        for (int mt = 0; mt < 4; mt++) af[mt]  = rdA(buf, wm + mt * 16 + r16, 4);
        #pragma unroll
        for (int nt = 0; nt < 4; nt++) bfr[nt] = rdB(buf, wn + nt * 16 + r16, 4);
        __builtin_amdgcn_s_barrier();
        asm volatile("s_waitcnt lgkmcnt(0)" ::: "memory");
        __builtin_amdgcn_sched_barrier(0);
        __builtin_amdgcn_s_setprio(1);
        #pragma unroll
        for (int mt = 0; mt < 4; mt++)
            #pragma unroll
            for (int nt = 0; nt < 4; nt++)
                acc[mt][nt] = __builtin_amdgcn_mfma_f32_16x16x32_bf16(af[mt], bfr[nt], acc[mt][nt], 0, 0, 0);
        __builtin_amdgcn_s_setprio(0);
        __builtin_amdgcn_s_barrier();

        // Phase 3: m-half1 x kk1
        #pragma unroll
        for (int mt = 0; mt < 4; mt++) af[mt] = rdA(buf, wm + (mt + 4) * 16 + r16, 4);
        __builtin_amdgcn_s_barrier();
        asm volatile("s_waitcnt lgkmcnt(0)" ::: "memory");
        __builtin_amdgcn_sched_barrier(0);
        __builtin_amdgcn_s_setprio(1);
        #pragma unroll
        for (int mt = 0; mt < 4; mt++)
            #pragma unroll
            for (int nt = 0; nt < 4; nt++)
                acc[mt + 4][nt] = __builtin_amdgcn_mfma_f32_16x16x32_bf16(af[mt], bfr[nt], acc[mt + 4][nt], 0, 0, 0);
        __builtin_amdgcn_s_setprio(0);
        __builtin_amdgcn_s_barrier();
    }
    #pragma unroll
    for (int mt = 0; mt < 8; mt++) {
        #pragma unroll
        for (int nt = 0; nt < 4; nt++) {
            int col = n0 + wn + nt * 16 + r16;
            float bv = (which == 3) ? bias[col] : 0.0f;
            #pragma unroll
            for (int r = 0; r < 4; r++) {
                int row = m0 + wm + mt * 16 + quad * 4 + r;
                float v = acc[mt][nt][r];
                if (which <= 1)      v = (v > 0.0f) ? v + 1.0f : __builtin_expf(v);     // phi = elu+1
                else if (which == 3) v = 1.0f / (1.0f + __builtin_expf(-(v + bv)));     // sigmoid gate
                Op[(size_t)row * HD_ + col] = f2bf(v);
            }
        }
    }
}

// ---------------- K5: output GEMM: Y = OG @ W_O^T (fp32 out), 256x128, 2-phase (round-3 form) ----------------
__global__ __launch_bounds__(512, 2) void k_gemm_out(
    const unsigned short* __restrict__ ogb, const unsigned short* __restrict__ wob,
    float* __restrict__ y)
{
    __shared__ unsigned short As[2][256 * 64];   // 64KB
    __shared__ unsigned short Bs[2][128 * 64];   // 32KB
    const int tid = threadIdx.x;
    const int id  = blockIdx.x;                  // 0..255
    const int xcd = id & 7, per = id >> 3;
    const int m0 = (xcd * 4 + (per & 3)) * 256;
    const int n0 = (per >> 2) * 128;
    const int K = HD_;                           // 512
    const int NIT = K / 64;                      // 8

    const int lane = tid & 63, wave = tid >> 6;  // 8 waves, 4M x 2N
    const int wm = (wave >> 1) * 64, wn = (wave & 1) * 64;
    const int r16 = lane & 15, quad = lane >> 4;
    const int lrow = lane >> 3, lseg = lane & 7;
    const int sseg = lseg ^ lrow;
    const int rx   = r16 & 7;

    f32x4 acc[4][4];
    #pragma unroll
    for (int a = 0; a < 4; a++)
        #pragma unroll
        for (int b = 0; b < 4; b++) acc[a][b] = 0.0f;

    auto stageA = [&](int buf, int ko_) {
        #pragma unroll
        for (int i = 0; i < 4; i++) {
            int chunk = wave * 4 + i;
            int row = chunk * 8 + lrow;
            gl_lds16(ogb + (size_t)(m0 + row) * K + ko_ + sseg * 8, &As[buf][chunk * 512]);
        }
    };
    auto stageB = [&](int buf, int ko_) {
        #pragma unroll
        for (int i = 0; i < 2; i++) {
            int chunk = wave * 2 + i;
            int row = chunk * 8 + lrow;
            gl_lds16(wob + (size_t)(n0 + row) * K + ko_ + sseg * 8, &Bs[buf][chunk * 512]);
        }
    };
    auto rdA = [&](int buf, int row, int gb) -> s16x8 {
        return *(const s16x8*)&As[buf][row * 64 + (((gb + quad) ^ rx) << 3)];
    };
    auto rdB = [&](int buf, int row, int gb) -> s16x8 {
        return *(const s16x8*)&Bs[buf][row * 64 + (((gb + quad) ^ rx) << 3)];
    };

    stageA(0, 0); stageB(0, 0);
    for (int it = 0; it < NIT; ++it) {
        const int buf = it & 1;
        asm volatile("s_waitcnt vmcnt(0)" ::: "memory");
        __builtin_amdgcn_s_barrier();

        s16x8 af[4], bfr[4];
        // Phase 0: kk0
        #pragma unroll
        for (int mt = 0; mt < 4; mt++) af[mt]  = rdA(buf, wm + mt * 16 + r16, 0);
        #pragma unroll
        for (int nt = 0; nt < 4; nt++) bfr[nt] = rdB(buf, wn + nt * 16 + r16, 0);
        if (it + 1 < NIT) stageA(buf ^ 1, (it + 1) * 64);
        __builtin_amdgcn_s_barrier();
        asm volatile("s_waitcnt lgkmcnt(0)" ::: "memory");
        __builtin_amdgcn_sched_barrier(0);
        __builtin_amdgcn_s_setprio(1);
        #pragma unroll
        for (int mt = 0; mt < 4; mt++)
            #pragma unroll
            for (int nt = 0; nt < 4; nt++)
                acc[mt][nt] = __builtin_amdgcn_mfma_f32_16x16x32_bf16(af[mt], bfr[nt], acc[mt][nt], 0, 0, 0);
        __builtin_amdgcn_s_setprio(0);
        __builtin_amdgcn_s_barrier();

        // Phase 1: kk1
        #pragma unroll
        for (int mt = 0; mt < 4; mt++) af[mt]  = rdA(buf, wm + mt * 16 + r16, 4);
        #pragma unroll
        for (int nt = 0; nt < 4; nt++) bfr[nt] = rdB(buf, wn + nt * 16 + r16, 4);
        if (it + 1 < NIT) stageB(buf ^ 1, (it + 1) * 64);
        __builtin_amdgcn_s_barrier();
        asm volatile("s_waitcnt lgkmcnt(0)" ::: "memory");
        __builtin_amdgcn_sched_barrier(0);
        __builtin_amdgcn_s_setprio(1);
        #pragma unroll
        for (int mt = 0; mt < 4; mt++)
            #pragma unroll
            for (int nt = 0; nt < 4; nt++)
                acc[mt][nt] = __builtin_amdgcn_mfma_f32_16x16x32_bf16(af[mt], bfr[nt], acc[mt][nt], 0, 0, 0);
        __builtin_amdgcn_s_setprio(0);
        __builtin_amdgcn_s_barrier();
    }
    #pragma unroll
    for (int mt = 0; mt < 4; mt++)
        #pragma unroll
        for (int nt = 0; nt < 4; nt++) {
            int col = n0 + wn + nt * 16 + r16;
            #pragma unroll
            for (int r = 0; r < 4; r++) {
                int row = m0 + wm + mt * 16 + quad * 4 + r;
                y[(size_t)row * D_ + col] = acc[mt][nt][r];
            }
        }
}

// ---------------- K2: fused recurrent chunk pipeline (replaces sums+scan+out) ----------------
// One block per (b,h); 8 waves; S (v-major, fp32) + z live in LDS across the 32-chunk loop.
// Per chunk: QK^T, carried=Q*S^T, PV, S-update all via 16x16x32 bf16 MFMA (16/wave/chunk).
__global__ __launch_bounds__(512) void k_chunk_fused(
    const unsigned short* __restrict__ Qb, const unsigned short* __restrict__ Kb,
    const unsigned short* __restrict__ Vb, const unsigned short* __restrict__ Gb,
    unsigned short* __restrict__ OGb, const float* __restrict__ decay_log)
{
    __shared__ unsigned short ql[64 * 72];   // q rows (t,d) bf16
    __shared__ unsigned short kl[64 * 72];   // k rows (t,d) bf16
    __shared__ unsigned short kt[64 * 72];   // k-hat transposed (d,t), decay folded
    __shared__ unsigned short vt[64 * 72];   // v transposed (d,t)
    __shared__ unsigned short pl[64 * 72];   // masked/decayed P (i,l) bf16
    __shared__ float stf[64 * 68];           // S^T state: stf[j][i], fp32
    __shared__ float den2[2][64];
    __shared__ float den_l[64];
    __shared__ float zl[64];
    __shared__ float gpow[CH_ + 1];

    const int tid = threadIdx.x;
    const int bh  = blockIdx.x;              // 0..31
    const int h   = bh & (H_ - 1);
    const int b   = bh >> 3;
    const float g  = 1.0f / (1.0f + __builtin_expf(-decay_log[h]));
    const float lg = __builtin_log2f(g);
    const float gC = __builtin_exp2f((float)CH_ * lg);   // gamma^64

    if (tid <= CH_) gpow[tid] = __builtin_exp2f((float)tid * lg);
    if (tid < DK_)  zl[tid] = 0.0f;
    for (int i = tid; i < 64 * 68; i += 512) stf[i] = 0.0f;

    const int lane = tid & 63, wave = tid >> 6;
    const int r16 = lane & 15, quad = lane >> 4;
    const int ib = wave & 3, half = wave >> 2;           // band index / tile-pair half

    const int lt_ = tid >> 3, ld0 = (tid & 7) * 8;       // staging coords (row, d-seg)
    const float wdec = __builtin_exp2f((float)(CH_ - 1 - lt_) * lg);  // gamma^(63-t)

    __syncthreads();

    // preload chunk 0 into regs
    size_t g0 = (size_t)(b * T_ + lt_) * HD_ + h * DK_ + ld0;
    uint4 qr = *(const uint4*)(Qb + g0);
    uint4 kr = *(const uint4*)(Kb + g0);
    uint4 vr = *(const uint4*)(Vb + g0);

    for (int c = 0; c < NC_; ++c) {
        const int t0 = c * CH_;
        // ---- stage current chunk from regs
        *(uint4*)&ql[lt_ * 72 + ld0] = qr;
        *(uint4*)&kl[lt_ * 72 + ld0] = kr;
        {
            const unsigned short* kp = (const unsigned short*)&kr;
            const unsigned short* vp = (const unsigned short*)&vr;
            #pragma unroll
            for (int j = 0; j < 8; j++) {
                kt[(ld0 + j) * 72 + lt_] = f2bf(bf2f(kp[j]) * wdec);
                vt[(ld0 + j) * 72 + lt_] = vp[j];
            }
        }
        __syncthreads();
        // ---- prefetch next chunk (lands under compute)
        if (c + 1 < NC_) {
            size_t gn = (size_t)(b * T_ + (c + 1) * CH_ + lt_) * HD_ + h * DK_ + ld0;
            qr = *(const uint4*)(Qb + gn);
            kr = *(const uint4*)(Kb + gn);
            vr = *(const uint4*)(Vb + gn);
        }

        // ---- SC = Q K^T : wave -> i-band ib, l-tiles {2*half, 2*half+1}
        f32x4 sc2[2];
        sc2[0] = 0.0f; sc2[1] = 0.0f;
        #pragma unroll
        for (int t2 = 0; t2 < 2; t2++) {
            int lt = 2 * half + t2;
            #pragma unroll
            for (int ks = 0; ks < 2; ks++) {
                s16x8 af  = *(const s16x8*)&ql[(16 * ib + r16) * 72 + ks * 32 + quad * 8];
                s16x8 bf_ = *(const s16x8*)&kl[(16 * lt + r16) * 72 + ks * 32 + quad * 8];
                sc2[t2] = __builtin_amdgcn_mfma_f32_16x16x32_bf16(af, bf_, sc2[t2], 0, 0, 0);
            }
        }
        // ---- mask/decay -> P (bf16, to LDS), intra row-sums
        float rs[4] = {0.0f, 0.0f, 0.0f, 0.0f};
        #pragma unroll
        for (int t2 = 0; t2 < 2; t2++) {
            int l = 16 * (2 * half + t2) + r16;
            #pragma unroll
            for (int rr = 0; rr < 4; rr++) {
                int i = 16 * ib + quad * 4 + rr;
                int diff = i - l;
                float val = (diff >= 0) ? sc2[t2][rr] * gpow[diff] : 0.0f;
                unsigned short pb = f2bf(val);
                pl[i * 72 + l] = pb;
                rs[rr] += bf2f(pb);          // den consistent with rounded P
            }
        }
        #pragma unroll
        for (int rr = 0; rr < 4; rr++) {
            float v_ = rs[rr];
            v_ += __shfl_xor(v_, 1);
            v_ += __shfl_xor(v_, 2);
            v_ += __shfl_xor(v_, 4);
            v_ += __shfl_xor(v_, 8);
            if (r16 == 0) den2[half][16 * ib + quad * 4 + rr] = v_;
        }
        __syncthreads();

        // ---- carried = Q * S_prev^T : out tiles (i-band ib, j-tiles 2*half+{0,1})
        f32x4 og2[2];
        #pragma unroll
        for (int t2 = 0; t2 < 2; t2++) {
            int jt = 2 * half + t2;
            f32x4 o = 0.0f;
            #pragma unroll
            for (int ks = 0; ks < 2; ks++) {
                s16x8 af = *(const s16x8*)&ql[(16 * ib + r16) * 72 + ks * 32 + quad * 8];
                const float* sp = &stf[(16 * jt + r16) * 68 + ks * 32 + quad * 8];
                s16x8 bf_;
                #pragma unroll
                for (int e = 0; e < 8; e++) bf_[e] = (short)f2bf(sp[e]);
                o = __builtin_amdgcn_mfma_f32_16x16x32_bf16(af, bf_, o, 0, 0, 0);
            }
            og2[t2] = o;
        }
        // scale carried by gamma^(i+1), then accumulate PV via MFMA
        #pragma unroll
        for (int t2 = 0; t2 < 2; t2++)
            #pragma unroll
            for (int rr = 0; rr < 4; rr++)
                og2[t2][rr] *= gpow[16 * ib + quad * 4 + rr + 1];
        #pragma unroll
        for (int t2 = 0; t2 < 2; t2++) {
            int jt = 2 * half + t2;
            #pragma unroll
            for (int ks = 0; ks < 2; ks++) {
                s16x8 af  = *(const s16x8*)&pl[(16 * ib + r16) * 72 + ks * 32 + quad * 8];
                s16x8 bf_ = *(const s16x8*)&vt[(16 * jt + r16) * 72 + ks * 32 + quad * 8];
                og2[t2] = __builtin_amdgcn_mfma_f32_16x16x32_bf16(af, bf_, og2[t2], 0, 0, 0);
            }
        }
        // ---- delta-S tiles (j-band ib, i-tiles 2*half+{0,1}); contraction over l
        f32x4 ds2[2];
        #pragma unroll
        for (int t2 = 0; t2 < 2; t2++) {
            int it_ = 2 * half + t2;
            f32x4 dd = 0.0f;
            #pragma unroll
            for (int ks = 0; ks < 2; ks++) {
                s16x8 af  = *(const s16x8*)&vt[(16 * ib + r16) * 72 + ks * 32 + quad * 8];
                s16x8 bf_ = *(const s16x8*)&kt[(16 * it_ + r16) * 72 + ks * 32 + quad * 8];
                dd = __builtin_amdgcn_mfma_f32_16x16x32_bf16(af, bf_, dd, 0, 0, 0);
            }
            ds2[t2] = dd;
        }
        // ---- denominator finalize: + gamma^(i+1) * q_i . z_prev + eps
        if (tid < DK_) {
            float dp = 0.0f;
            #pragma unroll
            for (int d8 = 0; d8 < 8; d8++) {
                uint4 qq = *(const uint4*)&ql[tid * 72 + d8 * 8];
                const unsigned short* qp = (const unsigned short*)&qq;
                #pragma unroll
                for (int e = 0; e < 8; e++) dp += bf2f(qp[e]) * zl[d8 * 8 + e];
            }
            den_l[tid] = den2[0][tid] + den2[1][tid] + gpow[tid + 1] * dp + EPS_;
        }
        __syncthreads();

        // ---- state update: stf = gC*stf + dS ; z = gC*z + rowsum(k-hat)
        #pragma unroll
        for (int t2 = 0; t2 < 2; t2++) {
            int it_ = 2 * half + t2;
            #pragma unroll
            for (int rr = 0; rr < 4; rr++) {
                int j = 16 * ib + quad * 4 + rr;
                float* sp = &stf[j * 68 + 16 * it_ + r16];
                *sp = gC * (*sp) + ds2[t2][rr];
            }
        }
        if (tid < DK_) {
            float zs = 0.0f;
            #pragma unroll
            for (int l8 = 0; l8 < 8; l8++) {
                uint4 kk = *(const uint4*)&kt[tid * 72 + l8 * 8];
                const unsigned short* kp = (const unsigned short*)&kk;
                #pragma unroll
                for (int e = 0; e < 8; e++) zs += bf2f(kp[e]);
            }
            zl[tid] = gC * zl[tid] + zs;
        }
        // ---- epilogue: gate * og / den -> global bf16
        #pragma unroll
        for (int t2 = 0; t2 < 2; t2++) {
            int j = 16 * (2 * half + t2) + r16;
            #pragma unroll
            for (int rr = 0; rr < 4; rr++) {
                int i = 16 * ib + quad * 4 + rr;
                float rcp = 1.0f / den_l[i];
                size_t ga = (size_t)(b * T_ + t0 + i) * HD_ + h * DK_ + j;
                float gate = bf2f(Gb[ga]);
                OGb[ga] = f2bf(og2[t2][rr] * rcp * gate);
            }
        }
        __syncthreads();   // protect ql/kl/kt/vt/pl/stf/zl before next chunk's staging
    }
}

// ---------------- host ----------------
extern "C" void kernel_launch(void* const* d_in, const int* in_sizes, int n_in,
                              void* d_out, int out_size, void* d_ws, size_t ws_size,
                              hipStream_t stream)
{
    (void)in_sizes; (void)n_in; (void)out_size; (void)ws_size;
    const float* x         = (const float*)d_in[0];
    const float* W_Q       = (const float*)d_in[1];
    const float* W_K       = (const float*)d_in[2];
    const float* W_V       = (const float*)d_in[3];
    const float* W_gw      = (const float*)d_in[4];
    const float* W_gb      = (const float*)d_in[5];
    const float* W_O       = (const float*)d_in[6];
    const float* decay_log = (const float*)d_in[7];
    float* y = (float*)d_out;

    char* ws = (char*)d_ws;
    size_t off = 0;
    auto alloc = [&](size_t bytes) { void* p = ws + off; off += (bytes + 255) & ~(size_t)255; return p; };
    unsigned short* xb   = (unsigned short*)alloc((size_t)B_ * T_ * D_ * 2);
    unsigned short* wqb  = (unsigned short*)alloc((size_t)HD_ * D_ * 2);
    unsigned short* wkb  = (unsigned short*)alloc((size_t)HD_ * D_ * 2);
    unsigned short* wvb  = (unsigned short*)alloc((size_t)HD_ * D_ * 2);
    unsigned short* wgb  = (unsigned short*)alloc((size_t)HD_ * D_ * 2);
    unsigned short* wob  = (unsigned short*)alloc((size_t)D_ * HD_ * 2);
    unsigned short* qb   = (unsigned short*)alloc((size_t)B_ * T_ * HD_ * 2);
    unsigned short* kb   = (unsigned short*)alloc((size_t)B_ * T_ * HD_ * 2);
    unsigned short* vb   = (unsigned short*)alloc((size_t)B_ * T_ * HD_ * 2);
    unsigned short* gb   = (unsigned short*)alloc((size_t)B_ * T_ * HD_ * 2);
    unsigned short* ogb  = (unsigned short*)alloc((size_t)B_ * T_ * HD_ * 2);

    k_cvt_all<<<8192 + 5 * 512, 256, 0, stream>>>(x, W_Q, W_K, W_V, W_gw, W_O,
                                                  xb, wqb, wkb, wvb, wgb, wob);
    k_gemm_qkvg<<<256, 512, 0, stream>>>(xb, wqb, wkb, wvb, wgb, W_gb, qb, kb, vb, gb);
    k_chunk_fused<<<B_ * H_, 512, 0, stream>>>(qb, kb, vb, gb, ogb, decay_log);
    k_gemm_out<<<256, 512, 0, stream>>>(ogb, wob, y);
}

// Round 6
// 205.434 us; speedup vs baseline: 1.5145x; 1.5145x over previous
//
#include <hip/hip_runtime.h>
#include <cstdint>
#include <cstddef>

#define B_   4
#define T_   2048
#define D_   1024
#define H_   8
#define DK_  64
#define HD_  512      // H*DK
#define CH_  64       // chunk length
#define NC_  32       // T_/CH_
#define EPS_ 1e-6f

typedef __attribute__((ext_vector_type(4))) float f32x4;
typedef __attribute__((ext_vector_type(8))) short s16x8;

__device__ __forceinline__ unsigned short f2bf(float f) {
    unsigned int x = __float_as_uint(f);
    unsigned int r = (x + 0x7FFFu + ((x >> 16) & 1u)) >> 16;
    return (unsigned short)r;
}
__device__ __forceinline__ float bf2f(unsigned short u) {
    return __uint_as_float(((unsigned int)u) << 16);
}
__device__ __forceinline__ void ld4(const float* p, float* o) {
    float4 v = *(const float4*)p; o[0]=v.x; o[1]=v.y; o[2]=v.z; o[3]=v.w;
}
// async global->LDS, 16B per lane; LDS dest = wave-uniform base + lane*16
__device__ __forceinline__ void gl_lds16(const unsigned short* g, unsigned short* l) {
    __builtin_amdgcn_global_load_lds(
        (const __attribute__((address_space(1))) unsigned int*)g,
        (__attribute__((address_space(3))) unsigned int*)l, 16, 0, 0);
}

// ---------------- K0: fused fp32 -> bf16 convert for all six tensors ----------------
__global__ __launch_bounds__(256) void k_cvt_all(
    const float* __restrict__ x,
    const float* __restrict__ wq, const float* __restrict__ wk,
    const float* __restrict__ wv, const float* __restrict__ wgw,
    const float* __restrict__ wo,
    unsigned short* __restrict__ xb,
    unsigned short* __restrict__ wqb, unsigned short* __restrict__ wkb,
    unsigned short* __restrict__ wvb, unsigned short* __restrict__ wgb,
    unsigned short* __restrict__ wob)
{
    int bid = blockIdx.x;
    const float* src; unsigned short* dst; int idx;
    if (bid < 8192) {
        src = x; dst = xb; idx = bid * 256 + threadIdx.x;
    } else {
        int r = bid - 8192;
        int w = r >> 9;
        idx = (r & 511) * 256 + threadIdx.x;
        switch (w) {
            case 0:  src = wq;  dst = wqb; break;
            case 1:  src = wk;  dst = wkb; break;
            case 2:  src = wv;  dst = wvb; break;
            case 3:  src = wgw; dst = wgb; break;
            default: src = wo;  dst = wob; break;
        }
    }
    float4 v = ((const float4*)src)[idx];
    ushort4 o;
    o.x = f2bf(v.x); o.y = f2bf(v.y); o.z = f2bf(v.z); o.w = f2bf(v.w);
    ((ushort4*)dst)[idx] = o;
}

// ---------------- K1: fused QKVG GEMM, 256x256 tile, counted-vmcnt pipeline (round-2 best-wall form) ----------------
__global__ __launch_bounds__(512, 2) void k_gemm_qkvg(
    const unsigned short* __restrict__ xb,
    const unsigned short* __restrict__ wqb, const unsigned short* __restrict__ wkb,
    const unsigned short* __restrict__ wvb, const unsigned short* __restrict__ wgb,
    const float* __restrict__ bias,
    unsigned short* __restrict__ qo, unsigned short* __restrict__ ko,
    unsigned short* __restrict__ vo, unsigned short* __restrict__ go)
{
    __shared__ unsigned short As[2][256 * 64];   // 64KB
    __shared__ unsigned short Bs[2][256 * 64];   // 64KB
    const int tid = threadIdx.x;
    const int id  = blockIdx.x;                  // 0..255
    const int xcd = id & 7, per = id >> 3;       // per 0..31
    const int mtile = xcd * 4 + (per & 3);       // 0..31
    const int ntile = per >> 2;                  // 0..7
    const int which = ntile >> 1;                // 0=Q 1=K 2=V 3=G
    const int nb    = ntile & 1;
    const int m0    = mtile * 256;
    const int n0    = nb * 256;
    const unsigned short* Wp = (which == 0) ? wqb : (which == 1) ? wkb : (which == 2) ? wvb : wgb;
    unsigned short* Op       = (which == 0) ? qo  : (which == 1) ? ko  : (which == 2) ? vo  : go;
    const int K = D_;
    const int NIT = K / 64;                      // 16

    const int lane = tid & 63, wave = tid >> 6;  // wave 0..7
    const int wm = (wave >> 2) * 128, wn = (wave & 3) * 64;
    const int r16 = lane & 15, quad = lane >> 4;
    const int lrow = lane >> 3, lseg = lane & 7;
    const int sseg = lseg ^ lrow;                // XOR swizzle
    const int rx   = r16 & 7;

    f32x4 acc[8][4];
    #pragma unroll
    for (int a = 0; a < 8; a++)
        #pragma unroll
        for (int b = 0; b < 4; b++) acc[a][b] = 0.0f;

    auto stage = [&](int buf, int ko_) {
        #pragma unroll
        for (int i = 0; i < 4; i++) {
            int chunk = wave * 4 + i;            // 0..31, wave-uniform
            int row = chunk * 8 + lrow;          // 0..255
            gl_lds16(xb + (size_t)(m0 + row) * K + ko_ + sseg * 8, &As[buf][chunk * 512]);
            gl_lds16(Wp + (size_t)(n0 + row) * K + ko_ + sseg * 8, &Bs[buf][chunk * 512]);
        }
    };

    stage(0, 0);
    for (int it = 0; it < NIT; ++it) {
        if (it + 1 < NIT) {
            stage((it + 1) & 1, (it + 1) * 64);
            asm volatile("s_waitcnt vmcnt(8)" ::: "memory");
        } else {
            asm volatile("s_waitcnt vmcnt(0)" ::: "memory");
        }
        __builtin_amdgcn_s_barrier();
        const int buf = it & 1;
        #pragma unroll
        for (int kk = 0; kk < 64; kk += 32) {
            const int gb_ = kk >> 3;
            s16x8 af[8], bf[4];
            #pragma unroll
            for (int mt = 0; mt < 8; mt++)
                af[mt] = *(const s16x8*)&As[buf][(wm + mt * 16 + r16) * 64 + (((gb_ + quad) ^ rx) << 3)];
            #pragma unroll
            for (int nt = 0; nt < 4; nt++)
                bf[nt] = *(const s16x8*)&Bs[buf][(wn + nt * 16 + r16) * 64 + (((gb_ + quad) ^ rx) << 3)];
            #pragma unroll
            for (int mt = 0; mt < 8; mt++)
                #pragma unroll
                for (int nt = 0; nt < 4; nt++)
                    acc[mt][nt] = __builtin_amdgcn_mfma_f32_16x16x32_bf16(af[mt], bf[nt], acc[mt][nt], 0, 0, 0);
        }
        __builtin_amdgcn_s_barrier();
    }
    #pragma unroll
    for (int mt = 0; mt < 8; mt++) {
        #pragma unroll
        for (int nt = 0; nt < 4; nt++) {
            int col = n0 + wn + nt * 16 + r16;
            float bv = (which == 3) ? bias[col] : 0.0f;
            #pragma unroll
            for (int r = 0; r < 4; r++) {
                int row = m0 + wm + mt * 16 + quad * 4 + r;
                float v = acc[mt][nt][r];
                if (which <= 1)      v = (v > 0.0f) ? v + 1.0f : __builtin_expf(v);     // phi = elu+1
                else if (which == 3) v = 1.0f / (1.0f + __builtin_expf(-(v + bv)));     // sigmoid gate
                Op[(size_t)row * HD_ + col] = f2bf(v);
            }
        }
    }
}

// ---------------- K5: output GEMM: Y = OG @ W_O^T (fp32 out), 256x128, counted vmcnt (round-2 form) ----------------
__global__ __launch_bounds__(512, 2) void k_gemm_out(
    const unsigned short* __restrict__ ogb, const unsigned short* __restrict__ wob,
    float* __restrict__ y)
{
    __shared__ unsigned short As[2][256 * 64];   // 64KB
    __shared__ unsigned short Bs[2][128 * 64];   // 32KB
    const int tid = threadIdx.x;
    const int id  = blockIdx.x;                  // 0..255
    const int xcd = id & 7, per = id >> 3;
    const int m0 = (xcd * 4 + (per & 3)) * 256;
    const int n0 = (per >> 2) * 128;
    const int K = HD_;                           // 512
    const int NIT = K / 64;                      // 8

    const int lane = tid & 63, wave = tid >> 6;  // 8 waves, 4M x 2N
    const int wm = (wave >> 1) * 64, wn = (wave & 1) * 64;
    const int r16 = lane & 15, quad = lane >> 4;
    const int lrow = lane >> 3, lseg = lane & 7;
    const int sseg = lseg ^ lrow;
    const int rx   = r16 & 7;

    f32x4 acc[4][4];
    #pragma unroll
    for (int a = 0; a < 4; a++)
        #pragma unroll
        for (int b = 0; b < 4; b++) acc[a][b] = 0.0f;

    auto stage = [&](int buf, int ko_) {
        #pragma unroll
        for (int i = 0; i < 4; i++) {
            int chunk = wave * 4 + i;
            int row = chunk * 8 + lrow;
            gl_lds16(ogb + (size_t)(m0 + row) * K + ko_ + sseg * 8, &As[buf][chunk * 512]);
        }
        #pragma unroll
        for (int i = 0; i < 2; i++) {
            int chunk = wave * 2 + i;
            int row = chunk * 8 + lrow;
            gl_lds16(wob + (size_t)(n0 + row) * K + ko_ + sseg * 8, &Bs[buf][chunk * 512]);
        }
    };

    stage(0, 0);
    for (int it = 0; it < NIT; ++it) {
        if (it + 1 < NIT) {
            stage((it + 1) & 1, (it + 1) * 64);
            asm volatile("s_waitcnt vmcnt(6)" ::: "memory");
        } else {
            asm volatile("s_waitcnt vmcnt(0)" ::: "memory");
        }
        __builtin_amdgcn_s_barrier();
        const int buf = it & 1;
        #pragma unroll
        for (int kk = 0; kk < 64; kk += 32) {
            const int gb_ = kk >> 3;
            s16x8 af[4], bf[4];
            #pragma unroll
            for (int mt = 0; mt < 4; mt++)
                af[mt] = *(const s16x8*)&As[buf][(wm + mt * 16 + r16) * 64 + (((gb_ + quad) ^ rx) << 3)];
            #pragma unroll
            for (int nt = 0; nt < 4; nt++)
                bf[nt] = *(const s16x8*)&Bs[buf][(wn + nt * 16 + r16) * 64 + (((gb_ + quad) ^ rx) << 3)];
            #pragma unroll
            for (int mt = 0; mt < 4; mt++)
                #pragma unroll
                for (int nt = 0; nt < 4; nt++)
                    acc[mt][nt] = __builtin_amdgcn_mfma_f32_16x16x32_bf16(af[mt], bf[nt], acc[mt][nt], 0, 0, 0);
        }
        __builtin_amdgcn_s_barrier();
    }
    #pragma unroll
    for (int mt = 0; mt < 4; mt++)
        #pragma unroll
        for (int nt = 0; nt < 4; nt++) {
            int col = n0 + wn + nt * 16 + r16;
            #pragma unroll
            for (int r = 0; r < 4; r++) {
                int row = m0 + wm + mt * 16 + quad * 4 + r;
                y[(size_t)row * D_ + col] = acc[mt][nt][r];
            }
        }
}

// ---------------- K2: per-chunk decayed sums (stores S^T for MFMA-friendly K4) ----------------
__global__ __launch_bounds__(256) void k_chunk_sums(
    const unsigned short* __restrict__ Kb, const unsigned short* __restrict__ Vb,
    float* __restrict__ Ssum, float* __restrict__ zsum, const float* __restrict__ decay_log)
{
    __shared__ float kl[CH_ * 68];
    __shared__ float vl[CH_ * 68];
    const int tid = threadIdx.x;
    const int bc  = blockIdx.x;            // bh*NC_ + c
    const int c   = bc & (NC_ - 1);
    const int bh  = bc >> 5;
    const int h   = bh & (H_ - 1);
    const int b   = bh >> 3;
    const float g  = 1.0f / (1.0f + __builtin_expf(-decay_log[h]));
    const float lg = __builtin_log2f(g);
    const int t0 = c * CH_;

    #pragma unroll
    for (int e = 0; e < 2; e++) {
        int lid = e * 256 + tid;
        int l = lid >> 3, d0 = (lid & 7) * 8;
        float w = __builtin_exp2f((float)(CH_ - 1 - l) * lg);
        size_t gidx = (size_t)(b * T_ + t0 + l) * HD_ + h * DK_ + d0;
        uint4 kraw = *(const uint4*)(Kb + gidx);
        uint4 vraw = *(const uint4*)(Vb + gidx);
        const unsigned short* kp = (const unsigned short*)&kraw;
        const unsigned short* vp = (const unsigned short*)&vraw;
        #pragma unroll
        for (int j = 0; j < 8; j++) {
            kl[l * 68 + d0 + j] = bf2f(kp[j]) * w;   // decay folded into k
            vl[l * 68 + d0 + j] = bf2f(vp[j]);
        }
    }
    __syncthreads();

    // swapped map so the TRANSPOSED store stays coalesced
    const int ti = tid & 15, tj = tid >> 4;
    const int i0 = ti * 4, j0 = tj * 4;       // i = k-dim, j = v-dim
    float acc[4][4];
    #pragma unroll
    for (int r = 0; r < 4; r++)
        #pragma unroll
        for (int cc = 0; cc < 4; cc++) acc[r][cc] = 0.0f;

    for (int l = 0; l < CH_; l++) {
        float kv[4], vv[4];
        ld4(&kl[l * 68 + i0], kv);
        ld4(&vl[l * 68 + j0], vv);
        #pragma unroll
        for (int r = 0; r < 4; r++)
            #pragma unroll
            for (int cc = 0; cc < 4; cc++) acc[r][cc] += kv[r] * vv[cc];
    }
    size_t base = (size_t)bc * (DK_ * DK_);
    #pragma unroll
    for (int cc = 0; cc < 4; cc++) {         // store S^T[j][i]
        float4 st = make_float4(acc[0][cc], acc[1][cc], acc[2][cc], acc[3][cc]);
        *(float4*)&Ssum[base + (size_t)(j0 + cc) * DK_ + i0] = st;
    }
    if (tid < DK_) {
        float s = 0.0f;
        for (int l = 0; l < CH_; l++) s += kl[l * 68 + tid];
        zsum[(size_t)bc * DK_ + tid] = s;
    }
}

// ---------------- K3: exclusive cross-chunk scan (in place; layout-agnostic) ----------------
__global__ __launch_bounds__(128) void k_chunk_scan(
    float* __restrict__ Ssum, float* __restrict__ zsum, const float* __restrict__ decay_log)
{
    const int tid = threadIdx.x;
    const int grp = blockIdx.x & 31;
    const int bh  = blockIdx.x >> 5;
    const int h   = bh & (H_ - 1);
    const float g  = 1.0f / (1.0f + __builtin_expf(-decay_log[h]));
    const float gC = __builtin_exp2f((float)CH_ * __builtin_log2f(g));   // gamma^CH
    int elem = grp * 128 + tid;                          // 0..4095
    float s = 0.0f;
    for (int c = 0; c < NC_; c++) {
        size_t idx = ((size_t)(bh * NC_ + c)) * 4096 + elem;
        float v = Ssum[idx];
        Ssum[idx] = s;
        s = gC * s + v;
    }
    if (grp == 0 && tid < DK_) {
        float z = 0.0f;
        for (int c = 0; c < NC_; c++) {
            size_t idx = ((size_t)(bh * NC_ + c)) * DK_ + tid;
            float v = zsum[idx];
            zsum[idx] = z;
            z = gC * z + v;
        }
    }
}

// ---------------- K4: per-chunk outputs — QK^T and Q*S^T via MFMA, PV via VALU ----------------
// 1024 blocks (b,h,c), 256 threads (4 waves, wave w owns i-band 16w..16w+15).
// MFMA fragment patterns identical to round-5's refcheck-passing kernel.
__global__ __launch_bounds__(256) void k_chunk_out(
    const unsigned short* __restrict__ Qb, const unsigned short* __restrict__ Kb,
    const unsigned short* __restrict__ Vb, const unsigned short* __restrict__ Gb,
    const float* __restrict__ Ssum, const float* __restrict__ zsum,
    unsigned short* __restrict__ OGb, const float* __restrict__ decay_log)
{
    __shared__ unsigned short ql[64 * 72];   // q rows (t,d) bf16
    __shared__ unsigned short kl[64 * 72];   // k rows (t,d) bf16
    __shared__ unsigned short sT[64 * 72];   // S_prev^T rows (j, d) bf16
    __shared__ float scT[64 * 68];           // P^T: scT[l][i] fp32
    __shared__ float vf [64 * 68];           // v rows fp32 [l][j]
    __shared__ float ogl[64 * 68];           // carried term [i][j] fp32 (scaled)
    __shared__ float den_l[64];
    __shared__ float zp[64];
    __shared__ float gpow[CH_ + 1];

    const int tid = threadIdx.x;
    const int bc  = blockIdx.x;
    const int c   = bc & (NC_ - 1);
    const int bh  = bc >> 5;
    const int h   = bh & (H_ - 1);
    const int b   = bh >> 3;
    const float g  = 1.0f / (1.0f + __builtin_expf(-decay_log[h]));
    const float lg = __builtin_log2f(g);
    const int t0 = c * CH_;

    if (tid <= CH_) gpow[tid] = __builtin_exp2f((float)tid * lg);
    if (tid < DK_)  zp[tid] = zsum[(size_t)bc * DK_ + tid];

    // ---- stage q,k rows (bf16) and v rows (fp32)
    #pragma unroll
    for (int e = 0; e < 2; e++) {
        int lid = e * 256 + tid;
        int l = lid >> 3, d0 = (lid & 7) * 8;
        size_t gidx = (size_t)(b * T_ + t0 + l) * HD_ + h * DK_ + d0;
        uint4 qraw = *(const uint4*)(Qb + gidx);
        uint4 kraw = *(const uint4*)(Kb + gidx);
        uint4 vraw = *(const uint4*)(Vb + gidx);
        *(uint4*)&ql[l * 72 + d0] = qraw;
        *(uint4*)&kl[l * 72 + d0] = kraw;
        const unsigned short* vp = (const unsigned short*)&vraw;
        #pragma unroll
        for (int j = 0; j < 8; j++) vf[l * 68 + d0 + j] = bf2f(vp[j]);
    }
    // ---- stage S_prev^T -> bf16 (validated numerically in round 5)
    {
        int j = tid >> 2, seg = tid & 3;
        const float4* src = (const float4*)&Ssum[(size_t)bc * 4096 + (size_t)j * 64 + seg * 16];
        #pragma unroll
        for (int e = 0; e < 4; e++) {
            float4 a4 = src[e];
            ushort4 o;
            o.x = f2bf(a4.x); o.y = f2bf(a4.y); o.z = f2bf(a4.z); o.w = f2bf(a4.w);
            *(ushort4*)&sT[j * 72 + seg * 16 + e * 4] = o;
        }
    }
    __syncthreads();

    const int lane = tid & 63, wave = tid >> 6;
    const int r16 = lane & 15, quad = lane >> 4;
    const int ibase = 16 * wave;

    // ---- SC = Q K^T (MFMA): wave's i-band x all 4 l-tiles
    f32x4 sc4[4];
    #pragma unroll
    for (int lt = 0; lt < 4; lt++) {
        f32x4 s = 0.0f;
        #pragma unroll
        for (int ks = 0; ks < 2; ks++) {
            s16x8 af  = *(const s16x8*)&ql[(ibase + r16) * 72 + ks * 32 + quad * 8];
            s16x8 bf_ = *(const s16x8*)&kl[(16 * lt + r16) * 72 + ks * 32 + quad * 8];
            s = __builtin_amdgcn_mfma_f32_16x16x32_bf16(af, bf_, s, 0, 0, 0);
        }
        sc4[lt] = s;
    }
    // mask + decay -> P (fp32, scT[l][i]) + intra row-sums
    float rs[4] = {0.0f, 0.0f, 0.0f, 0.0f};
    #pragma unroll
    for (int lt = 0; lt < 4; lt++) {
        int l = 16 * lt + r16;
        #pragma unroll
        for (int rr = 0; rr < 4; rr++) {
            int i = ibase + quad * 4 + rr;
            float val = (l <= i) ? sc4[lt][rr] * gpow[i - l] : 0.0f;
            scT[l * 68 + i] = val;
            rs[rr] += val;
        }
    }
    #pragma unroll
    for (int rr = 0; rr < 4; rr++) {
        float v_ = rs[rr];
        v_ += __shfl_xor(v_, 1);
        v_ += __shfl_xor(v_, 2);
        v_ += __shfl_xor(v_, 4);
        v_ += __shfl_xor(v_, 8);
        if (r16 == 0) den_l[ibase + quad * 4 + rr] = v_;
    }
    // ---- carried = Q * S_prev^T (MFMA), scale by gamma^(i+1), park in ogl
    #pragma unroll
    for (int jt = 0; jt < 4; jt++) {
        f32x4 o = 0.0f;
        #pragma unroll
        for (int ks = 0; ks < 2; ks++) {
            s16x8 af  = *(const s16x8*)&ql[(ibase + r16) * 72 + ks * 32 + quad * 8];
            s16x8 bf_ = *(const s16x8*)&sT[(16 * jt + r16) * 72 + ks * 32 + quad * 8];
            o = __builtin_amdgcn_mfma_f32_16x16x32_bf16(af, bf_, o, 0, 0, 0);
        }
        #pragma unroll
        for (int rr = 0; rr < 4; rr++) {
            int i = ibase + quad * 4 + rr;
            ogl[i * 68 + 16 * jt + r16] = o[rr] * gpow[i + 1];
        }
    }
    __syncthreads();

    // ---- denominator finalize: + gamma^(i+1) * q_i . z_prev + eps
    if (tid < DK_) {
        float dp = 0.0f;
        #pragma unroll
        for (int d8 = 0; d8 < 8; d8++) {
            uint4 qq = *(const uint4*)&ql[tid * 72 + d8 * 8];
            const unsigned short* qp = (const unsigned short*)&qq;
            #pragma unroll
            for (int e = 0; e < 8; e++) dp += bf2f(qp[e]) * zp[d8 * 8 + e];
        }
        den_l[tid] += gpow[tid + 1] * dp + EPS_;
    }
    __syncthreads();

    // ---- PV (VALU) + epilogue, (ti,tj) mapping
    const int ti = tid >> 4, tj = tid & 15;
    const int i0 = ti * 4, j0 = tj * 4;
    float og[4][4];
    #pragma unroll
    for (int r = 0; r < 4; r++) ld4(&ogl[(i0 + r) * 68 + j0], og[r]);

    for (int l = 0; l < CH_; l++) {
        float scv[4], vv[4];
        ld4(&scT[l * 68 + i0], scv);
        ld4(&vf[l * 68 + j0], vv);
        #pragma unroll
        for (int r = 0; r < 4; r++)
            #pragma unroll
            for (int cc = 0; cc < 4; cc++) og[r][cc] += scv[r] * vv[cc];
    }
    #pragma unroll
    for (int r = 0; r < 4; r++) {
        int i = i0 + r;
        float rcp = 1.0f / den_l[i];
        size_t gidx = (size_t)(b * T_ + t0 + i) * HD_ + h * DK_ + j0;
        ushort4 graw = *(const ushort4*)(Gb + gidx);
        ushort4 o;
        o.x = f2bf(og[r][0] * rcp * bf2f(graw.x));
        o.y = f2bf(og[r][1] * rcp * bf2f(graw.y));
        o.z = f2bf(og[r][2] * rcp * bf2f(graw.z));
        o.w = f2bf(og[r][3] * rcp * bf2f(graw.w));
        *(ushort4*)(OGb + gidx) = o;
    }
}

// ---------------- host ----------------
extern "C" void kernel_launch(void* const* d_in, const int* in_sizes, int n_in,
                              void* d_out, int out_size, void* d_ws, size_t ws_size,
                              hipStream_t stream)
{
    (void)in_sizes; (void)n_in; (void)out_size; (void)ws_size;
    const float* x         = (const float*)d_in[0];
    const float* W_Q       = (const float*)d_in[1];
    const float* W_K       = (const float*)d_in[2];
    const float* W_V       = (const float*)d_in[3];
    const float* W_gw      = (const float*)d_in[4];
    const float* W_gb      = (const float*)d_in[5];
    const float* W_O       = (const float*)d_in[6];
    const float* decay_log = (const float*)d_in[7];
    float* y = (float*)d_out;

    char* ws = (char*)d_ws;
    size_t off = 0;
    auto alloc = [&](size_t bytes) { void* p = ws + off; off += (bytes + 255) & ~(size_t)255; return p; };
    unsigned short* xb   = (unsigned short*)alloc((size_t)B_ * T_ * D_ * 2);
    unsigned short* wqb  = (unsigned short*)alloc((size_t)HD_ * D_ * 2);
    unsigned short* wkb  = (unsigned short*)alloc((size_t)HD_ * D_ * 2);
    unsigned short* wvb  = (unsigned short*)alloc((size_t)HD_ * D_ * 2);
    unsigned short* wgb  = (unsigned short*)alloc((size_t)HD_ * D_ * 2);
    unsigned short* wob  = (unsigned short*)alloc((size_t)D_ * HD_ * 2);
    unsigned short* qb   = (unsigned short*)alloc((size_t)B_ * T_ * HD_ * 2);
    unsigned short* kb   = (unsigned short*)alloc((size_t)B_ * T_ * HD_ * 2);
    unsigned short* vb   = (unsigned short*)alloc((size_t)B_ * T_ * HD_ * 2);
    unsigned short* gb   = (unsigned short*)alloc((size_t)B_ * T_ * HD_ * 2);
    unsigned short* ogb  = (unsigned short*)alloc((size_t)B_ * T_ * HD_ * 2);
    float* Ssum = (float*)alloc((size_t)B_ * H_ * NC_ * DK_ * DK_ * 4);
    float* zsum = (float*)alloc((size_t)B_ * H_ * NC_ * DK_ * 4);

    k_cvt_all<<<8192 + 5 * 512, 256, 0, stream>>>(x, W_Q, W_K, W_V, W_gw, W_O,
                                                  xb, wqb, wkb, wvb, wgb, wob);
    k_gemm_qkvg<<<256, 512, 0, stream>>>(xb, wqb, wkb, wvb, wgb, W_gb, qb, kb, vb, gb);
    k_chunk_sums<<<B_ * H_ * NC_, 256, 0, stream>>>(kb, vb, Ssum, zsum, decay_log);
    k_chunk_scan<<<B_ * H_ * NC_, 128, 0, stream>>>(Ssum, zsum, decay_log);
    k_chunk_out<<<B_ * H_ * NC_, 256, 0, stream>>>(qb, kb, vb, gb, Ssum, zsum, ogb, decay_log);
    k_gemm_out<<<256, 512, 0, stream>>>(ogb, wob, y);
}

// Round 7
// 197.869 us; speedup vs baseline: 1.5724x; 1.0382x over previous
//
#include <hip/hip_runtime.h>
#include <cstdint>
#include <cstddef>

#define B_   4
#define T_   2048
#define D_   1024
#define H_   8
#define DK_  64
#define HD_  512      // H*DK
#define CH_  64       // chunk length
#define NC_  32       // T_/CH_
#define EPS_ 1e-6f

typedef __attribute__((ext_vector_type(4))) float f32x4;
typedef __attribute__((ext_vector_type(8))) short s16x8;

__device__ __forceinline__ unsigned short f2bf(float f) {
    unsigned int x = __float_as_uint(f);
    unsigned int r = (x + 0x7FFFu + ((x >> 16) & 1u)) >> 16;
    return (unsigned short)r;
}
__device__ __forceinline__ float bf2f(unsigned short u) {
    return __uint_as_float(((unsigned int)u) << 16);
}
// async global->LDS, 16B per lane; LDS dest = wave-uniform base + lane*16
__device__ __forceinline__ void gl_lds16(const unsigned short* g, unsigned short* l) {
    __builtin_amdgcn_global_load_lds(
        (const __attribute__((address_space(1))) unsigned int*)g,
        (__attribute__((address_space(3))) unsigned int*)l, 16, 0, 0);
}

// ---------------- K0: fused fp32 -> bf16 convert for all six tensors ----------------
__global__ __launch_bounds__(256) void k_cvt_all(
    const float* __restrict__ x,
    const float* __restrict__ wq, const float* __restrict__ wk,
    const float* __restrict__ wv, const float* __restrict__ wgw,
    const float* __restrict__ wo,
    unsigned short* __restrict__ xb,
    unsigned short* __restrict__ wqb, unsigned short* __restrict__ wkb,
    unsigned short* __restrict__ wvb, unsigned short* __restrict__ wgb,
    unsigned short* __restrict__ wob)
{
    int bid = blockIdx.x;
    const float* src; unsigned short* dst; int idx;
    if (bid < 8192) {
        src = x; dst = xb; idx = bid * 256 + threadIdx.x;
    } else {
        int r = bid - 8192;
        int w = r >> 9;
        idx = (r & 511) * 256 + threadIdx.x;
        switch (w) {
            case 0:  src = wq;  dst = wqb; break;
            case 1:  src = wk;  dst = wkb; break;
            case 2:  src = wv;  dst = wvb; break;
            case 3:  src = wgw; dst = wgb; break;
            default: src = wo;  dst = wob; break;
        }
    }
    float4 v = ((const float4*)src)[idx];
    ushort4 o;
    o.x = f2bf(v.x); o.y = f2bf(v.y); o.z = f2bf(v.z); o.w = f2bf(v.w);
    ((ushort4*)dst)[idx] = o;
}

// ---------------- K1: fused QKVG GEMM, 256x256 tile, counted-vmcnt pipeline (best-wall form) ----------------
__global__ __launch_bounds__(512, 2) void k_gemm_qkvg(
    const unsigned short* __restrict__ xb,
    const unsigned short* __restrict__ wqb, const unsigned short* __restrict__ wkb,
    const unsigned short* __restrict__ wvb, const unsigned short* __restrict__ wgb,
    const float* __restrict__ bias,
    unsigned short* __restrict__ qo, unsigned short* __restrict__ ko,
    unsigned short* __restrict__ vo, unsigned short* __restrict__ go)
{
    __shared__ unsigned short As[2][256 * 64];   // 64KB
    __shared__ unsigned short Bs[2][256 * 64];   // 64KB
    const int tid = threadIdx.x;
    const int id  = blockIdx.x;                  // 0..255
    const int xcd = id & 7, per = id >> 3;       // per 0..31
    const int mtile = xcd * 4 + (per & 3);       // 0..31
    const int ntile = per >> 2;                  // 0..7
    const int which = ntile >> 1;                // 0=Q 1=K 2=V 3=G
    const int nb    = ntile & 1;
    const int m0    = mtile * 256;
    const int n0    = nb * 256;
    const unsigned short* Wp = (which == 0) ? wqb : (which == 1) ? wkb : (which == 2) ? wvb : wgb;
    unsigned short* Op       = (which == 0) ? qo  : (which == 1) ? ko  : (which == 2) ? vo  : go;
    const int K = D_;
    const int NIT = K / 64;                      // 16

    const int lane = tid & 63, wave = tid >> 6;  // wave 0..7
    const int wm = (wave >> 2) * 128, wn = (wave & 3) * 64;
    const int r16 = lane & 15, quad = lane >> 4;
    const int lrow = lane >> 3, lseg = lane & 7;
    const int sseg = lseg ^ lrow;                // XOR swizzle
    const int rx   = r16 & 7;

    f32x4 acc[8][4];
    #pragma unroll
    for (int a = 0; a < 8; a++)
        #pragma unroll
        for (int b = 0; b < 4; b++) acc[a][b] = 0.0f;

    auto stage = [&](int buf, int ko_) {
        #pragma unroll
        for (int i = 0; i < 4; i++) {
            int chunk = wave * 4 + i;            // 0..31, wave-uniform
            int row = chunk * 8 + lrow;          // 0..255
            gl_lds16(xb + (size_t)(m0 + row) * K + ko_ + sseg * 8, &As[buf][chunk * 512]);
            gl_lds16(Wp + (size_t)(n0 + row) * K + ko_ + sseg * 8, &Bs[buf][chunk * 512]);
        }
    };

    stage(0, 0);
    for (int it = 0; it < NIT; ++it) {
        if (it + 1 < NIT) {
            stage((it + 1) & 1, (it + 1) * 64);
            asm volatile("s_waitcnt vmcnt(8)" ::: "memory");
        } else {
            asm volatile("s_waitcnt vmcnt(0)" ::: "memory");
        }
        __builtin_amdgcn_s_barrier();
        const int buf = it & 1;
        #pragma unroll
        for (int kk = 0; kk < 64; kk += 32) {
            const int gb_ = kk >> 3;
            s16x8 af[8], bf[4];
            #pragma unroll
            for (int mt = 0; mt < 8; mt++)
                af[mt] = *(const s16x8*)&As[buf][(wm + mt * 16 + r16) * 64 + (((gb_ + quad) ^ rx) << 3)];
            #pragma unroll
            for (int nt = 0; nt < 4; nt++)
                bf[nt] = *(const s16x8*)&Bs[buf][(wn + nt * 16 + r16) * 64 + (((gb_ + quad) ^ rx) << 3)];
            #pragma unroll
            for (int mt = 0; mt < 8; mt++)
                #pragma unroll
                for (int nt = 0; nt < 4; nt++)
                    acc[mt][nt] = __builtin_amdgcn_mfma_f32_16x16x32_bf16(af[mt], bf[nt], acc[mt][nt], 0, 0, 0);
        }
        __builtin_amdgcn_s_barrier();
    }
    #pragma unroll
    for (int mt = 0; mt < 8; mt++) {
        #pragma unroll
        for (int nt = 0; nt < 4; nt++) {
            int col = n0 + wn + nt * 16 + r16;
            float bv = (which == 3) ? bias[col] : 0.0f;
            #pragma unroll
            for (int r = 0; r < 4; r++) {
                int row = m0 + wm + mt * 16 + quad * 4 + r;
                float v = acc[mt][nt][r];
                if (which <= 1)      v = (v > 0.0f) ? v + 1.0f : __builtin_expf(v);     // phi = elu+1
                else if (which == 3) v = 1.0f / (1.0f + __builtin_expf(-(v + bv)));     // sigmoid gate
                Op[(size_t)row * HD_ + col] = f2bf(v);
            }
        }
    }
}

// ---------------- K5: output GEMM: Y = OG @ W_O^T (fp32 out), 256x128, counted vmcnt ----------------
__global__ __launch_bounds__(512, 2) void k_gemm_out(
    const unsigned short* __restrict__ ogb, const unsigned short* __restrict__ wob,
    float* __restrict__ y)
{
    __shared__ unsigned short As[2][256 * 64];   // 64KB
    __shared__ unsigned short Bs[2][128 * 64];   // 32KB
    const int tid = threadIdx.x;
    const int id  = blockIdx.x;                  // 0..255
    const int xcd = id & 7, per = id >> 3;
    const int m0 = (xcd * 4 + (per & 3)) * 256;
    const int n0 = (per >> 2) * 128;
    const int K = HD_;                           // 512
    const int NIT = K / 64;                      // 8

    const int lane = tid & 63, wave = tid >> 6;  // 8 waves, 4M x 2N
    const int wm = (wave >> 1) * 64, wn = (wave & 1) * 64;
    const int r16 = lane & 15, quad = lane >> 4;
    const int lrow = lane >> 3, lseg = lane & 7;
    const int sseg = lseg ^ lrow;
    const int rx   = r16 & 7;

    f32x4 acc[4][4];
    #pragma unroll
    for (int a = 0; a < 4; a++)
        #pragma unroll
        for (int b = 0; b < 4; b++) acc[a][b] = 0.0f;

    auto stage = [&](int buf, int ko_) {
        #pragma unroll
        for (int i = 0; i < 4; i++) {
            int chunk = wave * 4 + i;
            int row = chunk * 8 + lrow;
            gl_lds16(ogb + (size_t)(m0 + row) * K + ko_ + sseg * 8, &As[buf][chunk * 512]);
        }
        #pragma unroll
        for (int i = 0; i < 2; i++) {
            int chunk = wave * 2 + i;
            int row = chunk * 8 + lrow;
            gl_lds16(wob + (size_t)(n0 + row) * K + ko_ + sseg * 8, &Bs[buf][chunk * 512]);
        }
    };

    stage(0, 0);
    for (int it = 0; it < NIT; ++it) {
        if (it + 1 < NIT) {
            stage((it + 1) & 1, (it + 1) * 64);
            asm volatile("s_waitcnt vmcnt(6)" ::: "memory");
        } else {
            asm volatile("s_waitcnt vmcnt(0)" ::: "memory");
        }
        __builtin_amdgcn_s_barrier();
        const int buf = it & 1;
        #pragma unroll
        for (int kk = 0; kk < 64; kk += 32) {
            const int gb_ = kk >> 3;
            s16x8 af[4], bf[4];
            #pragma unroll
            for (int mt = 0; mt < 4; mt++)
                af[mt] = *(const s16x8*)&As[buf][(wm + mt * 16 + r16) * 64 + (((gb_ + quad) ^ rx) << 3)];
            #pragma unroll
            for (int nt = 0; nt < 4; nt++)
                bf[nt] = *(const s16x8*)&Bs[buf][(wn + nt * 16 + r16) * 64 + (((gb_ + quad) ^ rx) << 3)];
            #pragma unroll
            for (int mt = 0; mt < 4; mt++)
                #pragma unroll
                for (int nt = 0; nt < 4; nt++)
                    acc[mt][nt] = __builtin_amdgcn_mfma_f32_16x16x32_bf16(af[mt], bf[nt], acc[mt][nt], 0, 0, 0);
        }
        __builtin_amdgcn_s_barrier();
    }
    #pragma unroll
    for (int mt = 0; mt < 4; mt++)
        #pragma unroll
        for (int nt = 0; nt < 4; nt++) {
            int col = n0 + wn + nt * 16 + r16;
            #pragma unroll
            for (int r = 0; r < 4; r++) {
                int row = m0 + wm + mt * 16 + quad * 4 + r;
                y[(size_t)row * D_ + col] = acc[mt][nt][r];
            }
        }
}

// ---------------- K2: per-chunk decayed sums via MFMA (stores S^T) ----------------
// 4096 blocks (b,h,c), 256 threads (4 waves). S^T[j][i] = sum_l v[l][j] * khat[l][i]
// via mfma(af = v^T row j over l, bf = khat^T row i over l). Fragment/output
// mapping identical to the round-5/6 refcheck-passing pattern.
__global__ __launch_bounds__(256) void k_chunk_sums(
    const unsigned short* __restrict__ Kb, const unsigned short* __restrict__ Vb,
    float* __restrict__ Ssum, float* __restrict__ zsum, const float* __restrict__ decay_log)
{
    __shared__ unsigned short kt[64 * 72];   // khat^T [d][l], decay folded, bf16
    __shared__ unsigned short vt[64 * 72];   // v^T    [d][l], bf16
    const int tid = threadIdx.x;
    const int bc  = blockIdx.x;            // bh*NC_ + c
    const int c   = bc & (NC_ - 1);
    const int bh  = bc >> 5;
    const int h   = bh & (H_ - 1);
    const int b   = bh >> 3;
    const float g  = 1.0f / (1.0f + __builtin_expf(-decay_log[h]));
    const float lg = __builtin_log2f(g);
    const int t0 = c * CH_;

    #pragma unroll
    for (int e = 0; e < 2; e++) {
        int lid = e * 256 + tid;           // 0..511 : 64 rows x 8 segs
        int l = lid >> 3, d0 = (lid & 7) * 8;
        float w = __builtin_exp2f((float)(CH_ - 1 - l) * lg);
        size_t gidx = (size_t)(b * T_ + t0 + l) * HD_ + h * DK_ + d0;
        uint4 kraw = *(const uint4*)(Kb + gidx);
        uint4 vraw = *(const uint4*)(Vb + gidx);
        const unsigned short* kp = (const unsigned short*)&kraw;
        const unsigned short* vp = (const unsigned short*)&vraw;
        #pragma unroll
        for (int j = 0; j < 8; j++) {
            kt[(d0 + j) * 72 + l] = f2bf(bf2f(kp[j]) * w);
            vt[(d0 + j) * 72 + l] = vp[j];
        }
    }
    __syncthreads();

    const int lane = tid & 63, wave = tid >> 6;
    const int r16 = lane & 15, quad = lane >> 4;
    size_t base = (size_t)bc * (DK_ * DK_);

    // wave owns j-band (16*wave .. +15); it = k-dim tile 0..3
    #pragma unroll
    for (int it = 0; it < 4; it++) {
        f32x4 sacc = 0.0f;
        #pragma unroll
        for (int ks = 0; ks < 2; ks++) {
            s16x8 af  = *(const s16x8*)&vt[(16 * wave + r16) * 72 + ks * 32 + quad * 8];
            s16x8 bf_ = *(const s16x8*)&kt[(16 * it   + r16) * 72 + ks * 32 + quad * 8];
            sacc = __builtin_amdgcn_mfma_f32_16x16x32_bf16(af, bf_, sacc, 0, 0, 0);
        }
        // C[j][i]: j = 16*wave + quad*4 + rr, i = 16*it + r16
        #pragma unroll
        for (int rr = 0; rr < 4; rr++)
            Ssum[base + (size_t)(16 * wave + quad * 4 + rr) * DK_ + 16 * it + r16] = sacc[rr];
    }
    if (tid < DK_) {
        float s = 0.0f;
        #pragma unroll
        for (int l8 = 0; l8 < 8; l8++) {
            uint4 kk = *(const uint4*)&kt[tid * 72 + l8 * 8];
            const unsigned short* kp = (const unsigned short*)&kk;
            #pragma unroll
            for (int e = 0; e < 8; e++) s += bf2f(kp[e]);
        }
        zsum[(size_t)bc * DK_ + tid] = s;
    }
}

// ---------------- K3: exclusive cross-chunk scan (in place; layout-agnostic) ----------------
__global__ __launch_bounds__(128) void k_chunk_scan(
    float* __restrict__ Ssum, float* __restrict__ zsum, const float* __restrict__ decay_log)
{
    const int tid = threadIdx.x;
    const int grp = blockIdx.x & 31;
    const int bh  = blockIdx.x >> 5;
    const int h   = bh & (H_ - 1);
    const float g  = 1.0f / (1.0f + __builtin_expf(-decay_log[h]));
    const float gC = __builtin_exp2f((float)CH_ * __builtin_log2f(g));   // gamma^CH
    int elem = grp * 128 + tid;                          // 0..4095
    float s = 0.0f;
    for (int c = 0; c < NC_; c++) {
        size_t idx = ((size_t)(bh * NC_ + c)) * 4096 + elem;
        float v = Ssum[idx];
        Ssum[idx] = s;
        s = gC * s + v;
    }
    if (grp == 0 && tid < DK_) {
        float z = 0.0f;
        for (int c = 0; c < NC_; c++) {
            size_t idx = ((size_t)(bh * NC_ + c)) * DK_ + tid;
            float v = zsum[idx];
            zsum[idx] = z;
            z = gC * z + v;
        }
    }
}

// ---------------- K4: per-chunk outputs — QK^T, Q*S^T, PV all via MFMA ----------------
// 1024 blocks (b,h,c), 256 threads (4 waves, wave w owns i-band 16w..16w+15).
// All fragment/output mappings identical to the round-5 refcheck-passing kernel.
__global__ __launch_bounds__(256) void k_chunk_out(
    const unsigned short* __restrict__ Qb, const unsigned short* __restrict__ Kb,
    const unsigned short* __restrict__ Vb, const unsigned short* __restrict__ Gb,
    const float* __restrict__ Ssum, const float* __restrict__ zsum,
    unsigned short* __restrict__ OGb, const float* __restrict__ decay_log)
{
    __shared__ unsigned short ql[64 * 72];   // q rows (t,d) bf16
    __shared__ unsigned short kl[64 * 72];   // k rows (t,d) bf16
    __shared__ unsigned short sT[64 * 72];   // S_prev^T rows (j over d) bf16
    __shared__ unsigned short vt[64 * 72];   // v^T [j][l] bf16
    __shared__ unsigned short pl[64 * 72];   // P [i][l] bf16 (masked/decayed)
    __shared__ float den_l[64];
    __shared__ float zp[64];
    __shared__ float gpow[CH_ + 1];

    const int tid = threadIdx.x;
    const int bc  = blockIdx.x;
    const int c   = bc & (NC_ - 1);
    const int bh  = bc >> 5;
    const int h   = bh & (H_ - 1);
    const int b   = bh >> 3;
    const float g  = 1.0f / (1.0f + __builtin_expf(-decay_log[h]));
    const float lg = __builtin_log2f(g);
    const int t0 = c * CH_;

    if (tid <= CH_) gpow[tid] = __builtin_exp2f((float)tid * lg);
    if (tid < DK_)  zp[tid] = zsum[(size_t)bc * DK_ + tid];

    // ---- stage q,k rows (vector); v transposed (scalar scatter)
    #pragma unroll
    for (int e = 0; e < 2; e++) {
        int lid = e * 256 + tid;
        int l = lid >> 3, d0 = (lid & 7) * 8;
        size_t gidx = (size_t)(b * T_ + t0 + l) * HD_ + h * DK_ + d0;
        uint4 qraw = *(const uint4*)(Qb + gidx);
        uint4 kraw = *(const uint4*)(Kb + gidx);
        uint4 vraw = *(const uint4*)(Vb + gidx);
        *(uint4*)&ql[l * 72 + d0] = qraw;
        *(uint4*)&kl[l * 72 + d0] = kraw;
        const unsigned short* vp = (const unsigned short*)&vraw;
        #pragma unroll
        for (int j = 0; j < 8; j++) vt[(d0 + j) * 72 + l] = vp[j];
    }
    // ---- stage S_prev^T -> bf16
    {
        int j = tid >> 2, seg = tid & 3;
        const float4* src = (const float4*)&Ssum[(size_t)bc * 4096 + (size_t)j * 64 + seg * 16];
        #pragma unroll
        for (int e = 0; e < 4; e++) {
            float4 a4 = src[e];
            ushort4 o;
            o.x = f2bf(a4.x); o.y = f2bf(a4.y); o.z = f2bf(a4.z); o.w = f2bf(a4.w);
            *(ushort4*)&sT[j * 72 + seg * 16 + e * 4] = o;
        }
    }
    __syncthreads();

    const int lane = tid & 63, wave = tid >> 6;
    const int r16 = lane & 15, quad = lane >> 4;
    const int ibase = 16 * wave;

    // hoisted q fragments (reused by QK^T, carried, and den below)
    s16x8 aq[2];
    #pragma unroll
    for (int ks = 0; ks < 2; ks++)
        aq[ks] = *(const s16x8*)&ql[(ibase + r16) * 72 + ks * 32 + quad * 8];

    // ---- SC = Q K^T (MFMA): wave's i-band x all 4 l-tiles
    f32x4 sc4[4];
    #pragma unroll
    for (int lt = 0; lt < 4; lt++) {
        f32x4 s = 0.0f;
        #pragma unroll
        for (int ks = 0; ks < 2; ks++) {
            s16x8 bf_ = *(const s16x8*)&kl[(16 * lt + r16) * 72 + ks * 32 + quad * 8];
            s = __builtin_amdgcn_mfma_f32_16x16x32_bf16(aq[ks], bf_, s, 0, 0, 0);
        }
        sc4[lt] = s;
    }
    // mask + decay -> P (bf16, pl[i][l], intra-wave rows) + intra row-sums
    float rs[4] = {0.0f, 0.0f, 0.0f, 0.0f};
    #pragma unroll
    for (int lt = 0; lt < 4; lt++) {
        int l = 16 * lt + r16;
        #pragma unroll
        for (int rr = 0; rr < 4; rr++) {
            int i = ibase + quad * 4 + rr;
            float val = (l <= i) ? sc4[lt][rr] * gpow[i - l] : 0.0f;
            unsigned short pb = f2bf(val);
            pl[i * 72 + l] = pb;
            rs[rr] += bf2f(pb);          // den consistent with rounded P
        }
    }
    #pragma unroll
    for (int rr = 0; rr < 4; rr++) {
        float v_ = rs[rr];
        v_ += __shfl_xor(v_, 1);
        v_ += __shfl_xor(v_, 2);
        v_ += __shfl_xor(v_, 4);
        v_ += __shfl_xor(v_, 8);
        if (r16 == 0) den_l[ibase + quad * 4 + rr] = v_;   // wave owns its band: no race
    }
    // ---- carried = Q * S_prev^T (MFMA), scale by gamma^(i+1)
    f32x4 og[4];
    #pragma unroll
    for (int jt = 0; jt < 4; jt++) {
        f32x4 o = 0.0f;
        #pragma unroll
        for (int ks = 0; ks < 2; ks++) {
            s16x8 bf_ = *(const s16x8*)&sT[(16 * jt + r16) * 72 + ks * 32 + quad * 8];
            o = __builtin_amdgcn_mfma_f32_16x16x32_bf16(aq[ks], bf_, o, 0, 0, 0);
        }
        #pragma unroll
        for (int rr = 0; rr < 4; rr++)
            o[rr] *= gpow[ibase + quad * 4 + rr + 1];
        og[jt] = o;
    }
    __syncthreads();   // den_l intra visible to all; pl/vt complete

    // ---- PV (MFMA): og[jt] += P * v^T — same output layout as carried
    #pragma unroll
    for (int jt = 0; jt < 4; jt++) {
        #pragma unroll
        for (int ks = 0; ks < 2; ks++) {
            s16x8 ap  = *(const s16x8*)&pl[(ibase + r16) * 72 + ks * 32 + quad * 8];
            s16x8 bf_ = *(const s16x8*)&vt[(16 * jt + r16) * 72 + ks * 32 + quad * 8];
            og[jt] = __builtin_amdgcn_mfma_f32_16x16x32_bf16(ap, bf_, og[jt], 0, 0, 0);
        }
    }
    // ---- denominator finalize: + gamma^(i+1) * q_i . z_prev + eps
    if (tid < DK_) {
        float dp = 0.0f;
        #pragma unroll
        for (int d8 = 0; d8 < 8; d8++) {
            uint4 qq = *(const uint4*)&ql[tid * 72 + d8 * 8];
            const unsigned short* qp = (const unsigned short*)&qq;
            #pragma unroll
            for (int e = 0; e < 8; e++) dp += bf2f(qp[e]) * zp[d8 * 8 + e];
        }
        den_l[tid] += gpow[tid + 1] * dp + EPS_;
    }
    __syncthreads();

    // ---- epilogue: gate * og / den -> global bf16 (i = ibase+quad*4+rr, j = 16jt+r16)
    #pragma unroll
    for (int jt = 0; jt < 4; jt++) {
        int j = 16 * jt + r16;
        #pragma unroll
        for (int rr = 0; rr < 4; rr++) {
            int i = ibase + quad * 4 + rr;
            float rcp = 1.0f / den_l[i];
            size_t ga = (size_t)(b * T_ + t0 + i) * HD_ + h * DK_ + j;
            float gate = bf2f(Gb[ga]);
            OGb[ga] = f2bf(og[jt][rr] * rcp * gate);
        }
    }
}

// ---------------- host ----------------
extern "C" void kernel_launch(void* const* d_in, const int* in_sizes, int n_in,
                              void* d_out, int out_size, void* d_ws, size_t ws_size,
                              hipStream_t stream)
{
    (void)in_sizes; (void)n_in; (void)out_size; (void)ws_size;
    const float* x         = (const float*)d_in[0];
    const float* W_Q       = (const float*)d_in[1];
    const float* W_K       = (const float*)d_in[2];
    const float* W_V       = (const float*)d_in[3];
    const float* W_gw      = (const float*)d_in[4];
    const float* W_gb      = (const float*)d_in[5];
    const float* W_O       = (const float*)d_in[6];
    const float* decay_log = (const float*)d_in[7];
    float* y = (float*)d_out;

    char* ws = (char*)d_ws;
    size_t off = 0;
    auto alloc = [&](size_t bytes) { void* p = ws + off; off += (bytes + 255) & ~(size_t)255; return p; };
    unsigned short* xb   = (unsigned short*)alloc((size_t)B_ * T_ * D_ * 2);
    unsigned short* wqb  = (unsigned short*)alloc((size_t)HD_ * D_ * 2);
    unsigned short* wkb  = (unsigned short*)alloc((size_t)HD_ * D_ * 2);
    unsigned short* wvb  = (unsigned short*)alloc((size_t)HD_ * D_ * 2);
    unsigned short* wgb  = (unsigned short*)alloc((size_t)HD_ * D_ * 2);
    unsigned short* wob  = (unsigned short*)alloc((size_t)D_ * HD_ * 2);
    unsigned short* qb   = (unsigned short*)alloc((size_t)B_ * T_ * HD_ * 2);
    unsigned short* kb   = (unsigned short*)alloc((size_t)B_ * T_ * HD_ * 2);
    unsigned short* vb   = (unsigned short*)alloc((size_t)B_ * T_ * HD_ * 2);
    unsigned short* gb   = (unsigned short*)alloc((size_t)B_ * T_ * HD_ * 2);
    unsigned short* ogb  = (unsigned short*)alloc((size_t)B_ * T_ * HD_ * 2);
    float* Ssum = (float*)alloc((size_t)B_ * H_ * NC_ * DK_ * DK_ * 4);
    float* zsum = (float*)alloc((size_t)B_ * H_ * NC_ * DK_ * 4);

    k_cvt_all<<<8192 + 5 * 512, 256, 0, stream>>>(x, W_Q, W_K, W_V, W_gw, W_O,
                                                  xb, wqb, wkb, wvb, wgb, wob);
    k_gemm_qkvg<<<256, 512, 0, stream>>>(xb, wqb, wkb, wvb, wgb, W_gb, qb, kb, vb, gb);
    k_chunk_sums<<<B_ * H_ * NC_, 256, 0, stream>>>(kb, vb, Ssum, zsum, decay_log);
    k_chunk_scan<<<B_ * H_ * NC_, 128, 0, stream>>>(Ssum, zsum, decay_log);
    k_chunk_out<<<B_ * H_ * NC_, 256, 0, stream>>>(qb, kb, vb, gb, Ssum, zsum, ogb, decay_log);
    k_gemm_out<<<256, 512, 0, stream>>>(ogb, wob, y);
}